// Round 4
// baseline (1134.929 us; speedup 1.0000x reference)
//
#include <hip/hip_runtime.h>
#include <hip/hip_bf16.h>

// BahdanauAttention: B=32, S=2048, H=1024, U=1024
//   q2 = query@W2 + b2                                  [B,U]
//   score[b,s] = sum_u tanh(values[b,s]@W1[:,u] + b1[u] + q2[b,u]) * V[u]  (+bv, softmax-invariant)
//   attn = softmax_s(score); context = sum_s attn * values
// Outputs concat: context [B,H]=32768 f32, attn [B,S,1]=65536 f32.
//
// score_gemm reads values fp32 directly and converts to bf16 at fragment-read
// time; context reads fp32 values. ws = W1T bf16 2MB + q2 f32 128KB only.

#define B_ 32
#define S_ 2048
#define H_ 1024
#define U_ 1024
#define M_ (B_ * S_)   // 65536

typedef __bf16 bf16;
typedef __bf16 bf16x8 __attribute__((ext_vector_type(8)));
typedef float  f32x4  __attribute__((ext_vector_type(4)));

__device__ __forceinline__ void gl2lds16(const void* g, void* l) {
    // 16B/lane direct global->LDS; lds ptr wave-uniform, lane*16 auto-offset
    __builtin_amdgcn_global_load_lds(
        (const __attribute__((address_space(1))) void*)g,
        (__attribute__((address_space(3))) void*)l, 16, 0, 0);
}

// ---------------- W1 [H,U] fp32 -> W1T [U,H] bf16 ----------------
__global__ void transpose_w1(const float* __restrict__ W1, bf16* __restrict__ W1T) {
    __shared__ bf16 t[64 * 65];
    int h0 = blockIdx.x * 64, u0 = blockIdx.y * 64;
    int tid = threadIdx.x;
    #pragma unroll
    for (int i = 0; i < 16; ++i) {
        int idx = i * 256 + tid;
        int r = idx >> 6, c = idx & 63;
        t[c * 65 + r] = (bf16)W1[(long)(h0 + r) * U_ + u0 + c];
    }
    __syncthreads();
    #pragma unroll
    for (int i = 0; i < 16; ++i) {
        int idx = i * 256 + tid;
        int r = idx >> 6, c = idx & 63;
        W1T[(long)(u0 + r) * H_ + h0 + c] = t[r * 65 + c];
    }
}

// ---------------- q2 = query@W2 + b2 ----------------
__global__ void q2_kernel(const float* __restrict__ query, const float* __restrict__ W2,
                          const float* __restrict__ b2, float* __restrict__ q2) {
    __shared__ float qsh[H_];
    __shared__ float part[4][64];
    int b = blockIdx.y;
    int u0 = blockIdx.x * 64;
    int tid = threadIdx.x;
    int ul = tid & 63, kc = tid >> 6;
    for (int i = tid; i < H_; i += 256) qsh[i] = query[b * H_ + i];
    __syncthreads();
    float acc = 0.f;
    const float* wp = W2 + (long)(kc * 256) * U_ + u0 + ul;
    #pragma unroll 8
    for (int h = 0; h < 256; ++h) acc += qsh[kc * 256 + h] * wp[(long)h * U_];
    part[kc][ul] = acc;
    __syncthreads();
    if (tid < 64)
        q2[b * U_ + u0 + tid] = part[0][tid] + part[1][tid] + part[2][tid] + part[3][tid]
                                + b2[u0 + tid];
}

// ---------------- fused GEMM + tanh + dot(V) ----------------
// 128x128 tile, BK=64 (two 32-k halves per barrier), 4 waves (2x2), 16x16x32 MFMA.
// A staged fp32 via global_load_lds (no pre-cast kernel), converted to bf16 at
// fragment read. Linear LDS layout (swizzle proven ineffective: fp32 row = 128B
// = all 32 banks; m97 reference carries same conflict count at 874 TF).
// XCD swizzle: same mt -> same blk%8 -> same XCD L2 (FETCH 530->102MB measured).
__global__ __launch_bounds__(256, 3) void score_gemm(
    const float* __restrict__ A32,  // values fp32 [M,H]
    const bf16* __restrict__ BT,    // W1T bf16 [U,H]
    const float* __restrict__ b1, const float* __restrict__ q2,
    const float* __restrict__ V, float* __restrict__ score /* [M] pre-zeroed */)
{
    __shared__ __align__(16) float a_sh[2 * 128 * 32];   // 32 KB, [hs][row][32]
    __shared__ __align__(16) bf16  b_sh[2 * 128 * 32];   // 16 KB, [hs][row][32]
    const int tid  = threadIdx.x;
    const int lane = tid & 63;
    const int wave = tid >> 6;
    const int wm = wave >> 1, wn = wave & 1;
    const int xcd = blockIdx.x & 7;
    const int i_  = blockIdx.x >> 3;          // 0..511
    const int nt  = i_ & 7;
    const int mt  = xcd * 64 + (i_ >> 3);     // 0..511
    const long m0 = (long)mt * 128;
    const int  n0 = nt * 128;
    const int lrow = lane & 15;
    const int quad = lane >> 4;

    f32x4 acc[4][4];
    const f32x4 zero = {0.f, 0.f, 0.f, 0.f};
    #pragma unroll
    for (int mi = 0; mi < 4; ++mi)
        #pragma unroll
        for (int ni = 0; ni < 4; ++ni) acc[mi][ni] = zero;

    const float* Abase = A32 + m0 * H_;
    const bf16*  Bbase = BT + (long)n0 * H_;

    for (int kt = 0; kt < H_; kt += 64) {
        // ---- stage A: 32 groups of 1KB (2 k-halves x 16), fp32, linear ----
        #pragma unroll
        for (int i = 0; i < 8; ++i) {
            int g  = i * 4 + wave;            // 0..31
            int hs = g >> 4, q = g & 15;
            int row = q * 8 + (lane >> 3);    // lane l -> row q*8+(l>>3), chunk l&7
            gl2lds16(Abase + (long)row * H_ + kt + hs * 32 + (lane & 7) * 4,
                     (void*)(a_sh + hs * 4096 + q * 256));
        }
        // ---- stage B: 16 groups of 1KB (2 k-halves x 8), bf16, linear ----
        #pragma unroll
        for (int i = 0; i < 4; ++i) {
            int g  = i * 4 + wave;            // 0..15
            int hs = g >> 3, q = g & 7;
            int row = q * 16 + (lane >> 2);   // lane l -> row q*16+(l>>2), chunk l&3
            gl2lds16(Bbase + (long)row * H_ + kt + hs * 32 + (lane & 3) * 8,
                     (void*)(b_sh + hs * 4096 + q * 512));
        }
        __syncthreads();

        #pragma unroll
        for (int hs = 0; hs < 2; ++hs) {
            bf16x8 af[4], bg[4];
            #pragma unroll
            for (int mi = 0; mi < 4; ++mi) {
                int r = wm * 64 + mi * 16 + lrow;
                const float4 lo = *reinterpret_cast<const float4*>(
                    a_sh + hs * 4096 + r * 32 + quad * 8);
                const float4 hi = *reinterpret_cast<const float4*>(
                    a_sh + hs * 4096 + r * 32 + quad * 8 + 4);
                bf16x8 f;
                f[0] = (bf16)lo.x; f[1] = (bf16)lo.y; f[2] = (bf16)lo.z; f[3] = (bf16)lo.w;
                f[4] = (bf16)hi.x; f[5] = (bf16)hi.y; f[6] = (bf16)hi.z; f[7] = (bf16)hi.w;
                af[mi] = f;
            }
            #pragma unroll
            for (int ni = 0; ni < 4; ++ni) {
                int r = wn * 64 + ni * 16 + lrow;
                bg[ni] = *reinterpret_cast<const bf16x8*>(
                    b_sh + hs * 4096 + r * 32 + quad * 8);
            }
            #pragma unroll
            for (int mi = 0; mi < 4; ++mi)
                #pragma unroll
                for (int ni = 0; ni < 4; ++ni)
                    acc[mi][ni] = __builtin_amdgcn_mfma_f32_16x16x32_bf16(
                        af[mi], bg[ni], acc[mi][ni], 0, 0, 0);
        }
        __syncthreads();
    }

    // epilogue: tanh(acc + b1 + q2) * V, reduce over u, atomic into score
    const int bb = (int)(m0 / S_);          // tile never straddles batches
    float bq[4], vv[4];
    #pragma unroll
    for (int ni = 0; ni < 4; ++ni) {
        int u = n0 + wn * 64 + ni * 16 + lrow;
        bq[ni] = b1[u] + q2[bb * U_ + u];
        vv[ni] = V[u];
    }
    #pragma unroll
    for (int mi = 0; mi < 4; ++mi) {
        #pragma unroll
        for (int r = 0; r < 4; ++r) {
            float s = 0.f;
            #pragma unroll
            for (int ni = 0; ni < 4; ++ni) {
                float x = acc[mi][ni][r] + bq[ni];
                float t = 1.f - 2.f / (__expf(2.f * x) + 1.f);   // tanh
                s += t * vv[ni];
            }
            s += __shfl_xor(s, 1); s += __shfl_xor(s, 2);
            s += __shfl_xor(s, 4); s += __shfl_xor(s, 8);
            if (lrow == 0)
                atomicAdd(score + m0 + wm * 64 + mi * 16 + quad * 4 + r, s);
        }
    }
}

// ---------------- softmax over s, in place ----------------
__global__ void softmax_kernel(float* __restrict__ attn) {
    __shared__ float sh[S_];
    __shared__ float red[8];
    int b = blockIdx.x, tid = threadIdx.x;
    float* row = attn + (long)b * S_;
    float lmax = -1e30f;
    for (int i = tid; i < S_; i += 256) { float v = row[i]; sh[i] = v; lmax = fmaxf(lmax, v); }
    #pragma unroll
    for (int m = 32; m; m >>= 1) lmax = fmaxf(lmax, __shfl_xor(lmax, m));
    if ((tid & 63) == 0) red[tid >> 6] = lmax;
    __syncthreads();
    float gmax = fmaxf(fmaxf(red[0], red[1]), fmaxf(red[2], red[3]));
    float lsum = 0.f;
    for (int i = tid; i < S_; i += 256) { float e = __expf(sh[i] - gmax); sh[i] = e; lsum += e; }
    #pragma unroll
    for (int m = 32; m; m >>= 1) lsum += __shfl_xor(lsum, m);
    if ((tid & 63) == 0) red[4 + (tid >> 6)] = lsum;
    __syncthreads();
    float inv = 1.f / (red[4] + red[5] + red[6] + red[7]);
    for (int i = tid; i < S_; i += 256) row[i] = sh[i] * inv;
}

// ---------------- context = sum_s attn * values (fp32 direct) ----------------
__global__ void context_kernel(const float* __restrict__ vals, const float* __restrict__ attn,
                               float* __restrict__ ctx /* pre-zeroed */) {
    __shared__ float a_sh[128];
    int b = blockIdx.x >> 4;
    int sc = blockIdx.x & 15;        // 16 s-chunks of 128
    int tid = threadIdx.x;
    if (tid < 128) a_sh[tid] = attn[(long)b * S_ + sc * 128 + tid];
    __syncthreads();
    const float* base = vals + ((long)b * S_ + sc * 128) * H_ + tid * 4;
    float ax = 0.f, ay = 0.f, az = 0.f, aw = 0.f;
    #pragma unroll 4
    for (int s = 0; s < 128; ++s) {
        float w = a_sh[s];
        float4 v = *reinterpret_cast<const float4*>(base + (long)s * H_);
        ax += w * v.x; ay += w * v.y; az += w * v.z; aw += w * v.w;
    }
    float* c = ctx + (long)b * H_ + tid * 4;
    atomicAdd(c + 0, ax); atomicAdd(c + 1, ay);
    atomicAdd(c + 2, az); atomicAdd(c + 3, aw);
}

extern "C" void kernel_launch(void* const* d_in, const int* in_sizes, int n_in,
                              void* d_out, int out_size, void* d_ws, size_t ws_size,
                              hipStream_t stream) {
    const float* query  = (const float*)d_in[0];
    const float* values = (const float*)d_in[1];
    const float* W1     = (const float*)d_in[2];
    const float* b1     = (const float*)d_in[3];
    const float* W2     = (const float*)d_in[4];
    const float* b2     = (const float*)d_in[5];
    const float* V      = (const float*)d_in[6];
    // d_in[7] = bv: softmax-invariant, context unaffected -> unused

    char* ws = (char*)d_ws;
    bf16*  w1t = (bf16*)ws;                                  // 2 MB
    float* q2  = (float*)(ws + (size_t)U_ * H_ * 2);         // 128 KB

    float* ctx  = (float*)d_out;            // [B,H]
    float* attn = (float*)d_out + B_ * H_;  // [B,S]

    hipMemsetAsync(d_out, 0, (size_t)(B_ * H_ + B_ * S_) * sizeof(float), stream);

    transpose_w1  <<<dim3(16, 16),       256, 0, stream>>>(W1, w1t);
    q2_kernel     <<<dim3(U_ / 64, B_),  256, 0, stream>>>(query, W2, b2, q2);
    score_gemm    <<<(M_ / 128) * 8,     256, 0, stream>>>(values, w1t, b1, q2, V, attn);
    softmax_kernel<<<B_,                 256, 0, stream>>>(attn);
    context_kernel<<<B_ * 16,            256, 0, stream>>>(values, attn, ctx);
}

// Round 5
// 605.194 us; speedup vs baseline: 1.8753x; 1.8753x over previous
//
#include <hip/hip_runtime.h>
#include <hip/hip_bf16.h>

// BahdanauAttention: B=32, S=2048, H=1024, U=1024
//   q2 = query@W2 + b2                                  [B,U]
//   score[b,s] = sum_u tanh(values[b,s]@W1[:,u] + b1[u] + q2[b,u]) * V[u]  (+bv, softmax-invariant)
//   attn = softmax_s(score); context = sum_s attn * values
// Outputs concat: context [B,H]=32768 f32, attn [B,S,1]=65536 f32.
//
// score_gemm reads values fp32 directly (XOR-swizzled LDS: proven necessary in
// R4 — removing it took SQ_LDS_BANK_CONFLICT 1.8e7 -> 3.7e8 and gemm 297->824us
// because a 128B fp32 row aliases all 16 quad-lanes onto 4 banks).
// context reads fp32 values. ws = W1T bf16 2MB + q2 f32 128KB only.

#define B_ 32
#define S_ 2048
#define H_ 1024
#define U_ 1024
#define M_ (B_ * S_)   // 65536

typedef __bf16 bf16;
typedef __bf16 bf16x8 __attribute__((ext_vector_type(8)));
typedef float  f32x4  __attribute__((ext_vector_type(4)));

__device__ __forceinline__ void gl2lds16(const void* g, void* l) {
    // 16B/lane direct global->LDS; lds ptr wave-uniform, lane*16 auto-offset
    __builtin_amdgcn_global_load_lds(
        (const __attribute__((address_space(1))) void*)g,
        (__attribute__((address_space(3))) void*)l, 16, 0, 0);
}

// ---------------- W1 [H,U] fp32 -> W1T [U,H] bf16 ----------------
__global__ void transpose_w1(const float* __restrict__ W1, bf16* __restrict__ W1T) {
    __shared__ bf16 t[64 * 65];
    int h0 = blockIdx.x * 64, u0 = blockIdx.y * 64;
    int tid = threadIdx.x;
    #pragma unroll
    for (int i = 0; i < 16; ++i) {
        int idx = i * 256 + tid;
        int r = idx >> 6, c = idx & 63;
        t[c * 65 + r] = (bf16)W1[(long)(h0 + r) * U_ + u0 + c];
    }
    __syncthreads();
    #pragma unroll
    for (int i = 0; i < 16; ++i) {
        int idx = i * 256 + tid;
        int r = idx >> 6, c = idx & 63;
        W1T[(long)(u0 + r) * H_ + h0 + c] = t[r * 65 + c];
    }
}

// ---------------- q2 = query@W2 + b2 ----------------
__global__ void q2_kernel(const float* __restrict__ query, const float* __restrict__ W2,
                          const float* __restrict__ b2, float* __restrict__ q2) {
    __shared__ float qsh[H_];
    __shared__ float part[4][64];
    int b = blockIdx.y;
    int u0 = blockIdx.x * 64;
    int tid = threadIdx.x;
    int ul = tid & 63, kc = tid >> 6;
    for (int i = tid; i < H_; i += 256) qsh[i] = query[b * H_ + i];
    __syncthreads();
    float acc = 0.f;
    const float* wp = W2 + (long)(kc * 256) * U_ + u0 + ul;
    #pragma unroll 8
    for (int h = 0; h < 256; ++h) acc += qsh[kc * 256 + h] * wp[(long)h * U_];
    part[kc][ul] = acc;
    __syncthreads();
    if (tid < 64)
        q2[b * U_ + u0 + tid] = part[0][tid] + part[1][tid] + part[2][tid] + part[3][tid]
                                + b2[u0 + tid];
}

// ---------------- fused GEMM + tanh + dot(V) ----------------
// 128x128 tile, BK=64 (two 32-k halves per barrier), 4 waves (2x2), 16x16x32 MFMA.
// A staged fp32 via global_load_lds, XOR-swizzled (stored 16B-chunk p of row r
// holds global chunk p^(r&7)); B bf16, stored chunk p holds global p^((r>>1)&3).
// Both make fragment ds_read_b128 conflict-free. XCD swizzle: same mt -> same
// blk%8 -> same XCD L2 (FETCH 530->102MB measured in R2).
__global__ __launch_bounds__(256, 3) void score_gemm(
    const float* __restrict__ A32,  // values fp32 [M,H]
    const bf16* __restrict__ BT,    // W1T bf16 [U,H]
    const float* __restrict__ b1, const float* __restrict__ q2,
    const float* __restrict__ V, float* __restrict__ score /* [M] pre-zeroed */)
{
    __shared__ __align__(16) float a_sh[2 * 128 * 32];   // 32 KB, [hs][row][32]
    __shared__ __align__(16) bf16  b_sh[2 * 128 * 32];   // 16 KB, [hs][row][32]
    const int tid  = threadIdx.x;
    const int lane = tid & 63;
    const int wave = tid >> 6;
    const int wm = wave >> 1, wn = wave & 1;
    const int xcd = blockIdx.x & 7;
    const int i_  = blockIdx.x >> 3;          // 0..511
    const int nt  = i_ & 7;
    const int mt  = xcd * 64 + (i_ >> 3);     // 0..511
    const long m0 = (long)mt * 128;
    const int  n0 = nt * 128;
    const int lrow = lane & 15;
    const int quad = lane >> 4;

    f32x4 acc[4][4];
    const f32x4 zero = {0.f, 0.f, 0.f, 0.f};
    #pragma unroll
    for (int mi = 0; mi < 4; ++mi)
        #pragma unroll
        for (int ni = 0; ni < 4; ++ni) acc[mi][ni] = zero;

    const float* Abase = A32 + m0 * H_;
    const bf16*  Bbase = BT + (long)n0 * H_;

    for (int kt = 0; kt < H_; kt += 64) {
        // ---- stage A: 32 groups of 1KB (2 k-halves x 16), fp32, swizzled ----
        #pragma unroll
        for (int i = 0; i < 8; ++i) {
            int g  = i * 4 + wave;            // 0..31
            int hs = g >> 4, q = g & 15;
            int row = q * 8 + (lane >> 3);    // 0..127
            int gc  = (lane & 7) ^ (row & 7); // global 16B-chunk index
            gl2lds16(Abase + (long)row * H_ + kt + hs * 32 + gc * 4,
                     (void*)(a_sh + hs * 4096 + q * 256));
        }
        // ---- stage B: 16 groups of 1KB (2 k-halves x 8), bf16, swizzled ----
        #pragma unroll
        for (int i = 0; i < 4; ++i) {
            int g  = i * 4 + wave;            // 0..15
            int hs = g >> 3, q = g & 7;
            int row = q * 16 + (lane >> 2);   // 0..127
            int gc  = (lane & 3) ^ ((row >> 1) & 3);
            gl2lds16(Bbase + (long)row * H_ + kt + hs * 32 + gc * 8,
                     (void*)(b_sh + hs * 4096 + q * 512));
        }
        __syncthreads();

        #pragma unroll
        for (int hs = 0; hs < 2; ++hs) {
            bf16x8 af[4], bg[4];
            #pragma unroll
            for (int mi = 0; mi < 4; ++mi) {
                int r  = wm * 64 + mi * 16 + lrow;
                int p0 = (2 * quad) ^ (r & 7);
                const float4 lo = *reinterpret_cast<const float4*>(
                    a_sh + hs * 4096 + r * 32 + p0 * 4);
                const float4 hi = *reinterpret_cast<const float4*>(
                    a_sh + hs * 4096 + r * 32 + (p0 ^ 1) * 4);
                bf16x8 f;
                f[0] = (bf16)lo.x; f[1] = (bf16)lo.y; f[2] = (bf16)lo.z; f[3] = (bf16)lo.w;
                f[4] = (bf16)hi.x; f[5] = (bf16)hi.y; f[6] = (bf16)hi.z; f[7] = (bf16)hi.w;
                af[mi] = f;
            }
            #pragma unroll
            for (int ni = 0; ni < 4; ++ni) {
                int r = wn * 64 + ni * 16 + lrow;
                int p = quad ^ ((r >> 1) & 3);
                bg[ni] = *reinterpret_cast<const bf16x8*>(
                    b_sh + hs * 4096 + r * 32 + p * 8);
            }
            #pragma unroll
            for (int mi = 0; mi < 4; ++mi)
                #pragma unroll
                for (int ni = 0; ni < 4; ++ni)
                    acc[mi][ni] = __builtin_amdgcn_mfma_f32_16x16x32_bf16(
                        af[mi], bg[ni], acc[mi][ni], 0, 0, 0);
        }
        __syncthreads();
    }

    // epilogue: tanh(acc + b1 + q2) * V, reduce over u, atomic into score
    const int bb = (int)(m0 / S_);          // tile never straddles batches
    float bq[4], vv[4];
    #pragma unroll
    for (int ni = 0; ni < 4; ++ni) {
        int u = n0 + wn * 64 + ni * 16 + lrow;
        bq[ni] = b1[u] + q2[bb * U_ + u];
        vv[ni] = V[u];
    }
    #pragma unroll
    for (int mi = 0; mi < 4; ++mi) {
        #pragma unroll
        for (int r = 0; r < 4; ++r) {
            float s = 0.f;
            #pragma unroll
            for (int ni = 0; ni < 4; ++ni) {
                float x = acc[mi][ni][r] + bq[ni];
                float t = 1.f - 2.f / (__expf(2.f * x) + 1.f);   // tanh
                s += t * vv[ni];
            }
            s += __shfl_xor(s, 1); s += __shfl_xor(s, 2);
            s += __shfl_xor(s, 4); s += __shfl_xor(s, 8);
            if (lrow == 0)
                atomicAdd(score + m0 + wm * 64 + mi * 16 + quad * 4 + r, s);
        }
    }
}

// ---------------- softmax over s, in place ----------------
__global__ void softmax_kernel(float* __restrict__ attn) {
    __shared__ float sh[S_];
    __shared__ float red[8];
    int b = blockIdx.x, tid = threadIdx.x;
    float* row = attn + (long)b * S_;
    float lmax = -1e30f;
    for (int i = tid; i < S_; i += 256) { float v = row[i]; sh[i] = v; lmax = fmaxf(lmax, v); }
    #pragma unroll
    for (int m = 32; m; m >>= 1) lmax = fmaxf(lmax, __shfl_xor(lmax, m));
    if ((tid & 63) == 0) red[tid >> 6] = lmax;
    __syncthreads();
    float gmax = fmaxf(fmaxf(red[0], red[1]), fmaxf(red[2], red[3]));
    float lsum = 0.f;
    for (int i = tid; i < S_; i += 256) { float e = __expf(sh[i] - gmax); sh[i] = e; lsum += e; }
    #pragma unroll
    for (int m = 32; m; m >>= 1) lsum += __shfl_xor(lsum, m);
    if ((tid & 63) == 0) red[4 + (tid >> 6)] = lsum;
    __syncthreads();
    float inv = 1.f / (red[4] + red[5] + red[6] + red[7]);
    for (int i = tid; i < S_; i += 256) row[i] = sh[i] * inv;
}

// ---------------- context = sum_s attn * values (fp32 direct) ----------------
__global__ void context_kernel(const float* __restrict__ vals, const float* __restrict__ attn,
                               float* __restrict__ ctx /* pre-zeroed */) {
    __shared__ float a_sh[128];
    int b = blockIdx.x >> 4;
    int sc = blockIdx.x & 15;        // 16 s-chunks of 128
    int tid = threadIdx.x;
    if (tid < 128) a_sh[tid] = attn[(long)b * S_ + sc * 128 + tid];
    __syncthreads();
    const float* base = vals + ((long)b * S_ + sc * 128) * H_ + tid * 4;
    float ax = 0.f, ay = 0.f, az = 0.f, aw = 0.f;
    #pragma unroll 4
    for (int s = 0; s < 128; ++s) {
        float w = a_sh[s];
        float4 v = *reinterpret_cast<const float4*>(base + (long)s * H_);
        ax += w * v.x; ay += w * v.y; az += w * v.z; aw += w * v.w;
    }
    float* c = ctx + (long)b * H_ + tid * 4;
    atomicAdd(c + 0, ax); atomicAdd(c + 1, ay);
    atomicAdd(c + 2, az); atomicAdd(c + 3, aw);
}

extern "C" void kernel_launch(void* const* d_in, const int* in_sizes, int n_in,
                              void* d_out, int out_size, void* d_ws, size_t ws_size,
                              hipStream_t stream) {
    const float* query  = (const float*)d_in[0];
    const float* values = (const float*)d_in[1];
    const float* W1     = (const float*)d_in[2];
    const float* b1     = (const float*)d_in[3];
    const float* W2     = (const float*)d_in[4];
    const float* b2     = (const float*)d_in[5];
    const float* V      = (const float*)d_in[6];
    // d_in[7] = bv: softmax-invariant, context unaffected -> unused

    char* ws = (char*)d_ws;
    bf16*  w1t = (bf16*)ws;                                  // 2 MB
    float* q2  = (float*)(ws + (size_t)U_ * H_ * 2);         // 128 KB

    float* ctx  = (float*)d_out;            // [B,H]
    float* attn = (float*)d_out + B_ * H_;  // [B,S]

    hipMemsetAsync(d_out, 0, (size_t)(B_ * H_ + B_ * S_) * sizeof(float), stream);

    transpose_w1  <<<dim3(16, 16),       256, 0, stream>>>(W1, w1t);
    q2_kernel     <<<dim3(U_ / 64, B_),  256, 0, stream>>>(query, W2, b2, q2);
    score_gemm    <<<(M_ / 128) * 8,     256, 0, stream>>>(values, w1t, b1, q2, V, attn);
    softmax_kernel<<<B_,                 256, 0, stream>>>(attn);
    context_kernel<<<B_ * 16,            256, 0, stream>>>(values, attn, ctx);
}

// Round 6
// 596.937 us; speedup vs baseline: 1.9013x; 1.0138x over previous
//
#include <hip/hip_runtime.h>
#include <hip/hip_bf16.h>

// BahdanauAttention: B=32, S=2048, H=1024, U=1024
//   q2 = query@W2 + b2                                  [B,U]
//   score[b,s] = sum_u tanh(values[b,s]@W1[:,u] + b1[u] + q2[b,u]) * V[u]  (+bv, softmax-invariant)
//   attn = softmax_s(score); context = sum_s attn * values
// Outputs concat: context [B,H]=32768 f32, attn [B,S,1]=65536 f32.
//
// score_gemm v2: A staged f32 global->VGPR, packed-cvt to bf16 ONCE per element,
// ds_write into LDS with padded row stride 40 bf16 (80B -> bank 20r+4q, conflict
// free; padding legal for ds_write, NOT for global_load_lds). B: gl2lds16 + XOR
// swizzle (removal proven 21x conflict blowup in R4). XCD swizzle keeps A-tile
// in one XCD's L2 (FETCH 530->102MB, R2).

#define B_ 32
#define S_ 2048
#define H_ 1024
#define U_ 1024
#define M_ (B_ * S_)   // 65536

typedef __bf16 bf16;
typedef __bf16 bf16x8 __attribute__((ext_vector_type(8)));
typedef float  f32x4  __attribute__((ext_vector_type(4)));

__device__ __forceinline__ void gl2lds16(const void* g, void* l) {
    __builtin_amdgcn_global_load_lds(
        (const __attribute__((address_space(1))) void*)g,
        (__attribute__((address_space(3))) void*)l, 16, 0, 0);
}

__device__ __forceinline__ bf16x8 cvt8(float4 a, float4 b) {
    bf16x8 o;
    o[0] = (bf16)a.x; o[1] = (bf16)a.y; o[2] = (bf16)a.z; o[3] = (bf16)a.w;
    o[4] = (bf16)b.x; o[5] = (bf16)b.y; o[6] = (bf16)b.z; o[7] = (bf16)b.w;
    return o;
}

// ---------------- prep: W1 transpose-cast (blocks 0..255) + q2 (blocks 256..767) ----------------
__global__ void prep_kernel(const float* __restrict__ W1, bf16* __restrict__ W1T,
                            const float* __restrict__ query, const float* __restrict__ W2,
                            const float* __restrict__ b2, float* __restrict__ q2) {
    __shared__ __align__(16) char smem[64 * 65 * 2];   // 8320 B, union of both uses
    int tid = threadIdx.x;
    if (blockIdx.x < 256) {
        // ---- W1 [H,U] fp32 -> W1T [U,H] bf16 ----
        bf16* t = (bf16*)smem;
        int h0 = (blockIdx.x >> 4) * 64, u0 = (blockIdx.x & 15) * 64;
        #pragma unroll
        for (int i = 0; i < 16; ++i) {
            int idx = i * 256 + tid;
            int r = idx >> 6, c = idx & 63;
            t[c * 65 + r] = (bf16)W1[(long)(h0 + r) * U_ + u0 + c];
        }
        __syncthreads();
        #pragma unroll
        for (int i = 0; i < 16; ++i) {
            int idx = i * 256 + tid;
            int r = idx >> 6, c = idx & 63;
            W1T[(long)(u0 + r) * H_ + h0 + c] = t[r * 65 + c];
        }
    } else {
        // ---- q2 = query@W2 + b2 ----
        float* qsh  = (float*)smem;            // 4 KB
        float* part = (float*)(smem + 4096);   // 4x64 f32 = 1 KB
        int idx = blockIdx.x - 256;            // 0..511
        int b  = idx >> 4;
        int u0 = (idx & 15) * 64;
        int ul = tid & 63, kc = tid >> 6;
        for (int i = tid; i < H_; i += 256) qsh[i] = query[b * H_ + i];
        __syncthreads();
        float acc = 0.f;
        const float* wp = W2 + (long)(kc * 256) * U_ + u0 + ul;
        #pragma unroll 8
        for (int h = 0; h < 256; ++h) acc += qsh[kc * 256 + h] * wp[(long)h * U_];
        part[kc * 64 + ul] = acc;
        __syncthreads();
        if (tid < 64)
            q2[b * U_ + u0 + tid] = part[tid] + part[64 + tid] + part[128 + tid]
                                    + part[192 + tid] + b2[u0 + tid];
    }
}

// ---------------- fused GEMM + tanh + dot(V) ----------------
// 128x128 tile, BK=64 (two 32-k halves), 4 waves (2x2), 16x16x32 bf16 MFMA.
#define ASTRIDE 40   // bf16 elems per A row in LDS (32 used + 8 pad)
__global__ __launch_bounds__(256, 3) void score_gemm(
    const float* __restrict__ A32,  // values fp32 [M,H]
    const bf16* __restrict__ BT,    // W1T bf16 [U,H]
    const float* __restrict__ b1, const float* __restrict__ q2,
    const float* __restrict__ V, float* __restrict__ score /* [M] pre-zeroed */)
{
    __shared__ __align__(16) bf16 a_sh[2 * 128 * ASTRIDE];   // 20 KB
    __shared__ __align__(16) bf16 b_sh[2 * 128 * 32];        // 16 KB
    const int tid  = threadIdx.x;
    const int lane = tid & 63;
    const int wave = tid >> 6;
    const int wm = wave >> 1, wn = wave & 1;
    const int xcd = blockIdx.x & 7;
    const int i_  = blockIdx.x >> 3;
    const int nt  = i_ & 7;
    const int mt  = xcd * 64 + (i_ >> 3);
    const long m0 = (long)mt * 128;
    const int  n0 = nt * 128;
    const int lrow = lane & 15;
    const int quad = lane >> 4;
    const int arow = tid >> 1;       // A cvt ownership: 128 rows x 2 segs
    const int aseg = tid & 1;        // 16 f32 per (row,seg)

    f32x4 acc[4][4];
    const f32x4 zero = {0.f, 0.f, 0.f, 0.f};
    #pragma unroll
    for (int mi = 0; mi < 4; ++mi)
        #pragma unroll
        for (int ni = 0; ni < 4; ++ni) acc[mi][ni] = zero;

    const float* Abase = A32 + m0 * H_;
    const bf16*  Bbase = BT + (long)n0 * H_;

    for (int kt = 0; kt < H_; kt += 64) {
        // ---- stage B: async gl2lds, XOR-swizzled (stored chunk p = g^((r>>1)&3)) ----
        #pragma unroll
        for (int i = 0; i < 4; ++i) {
            int g  = i * 4 + wave;            // 0..15
            int hs = g >> 3, q = g & 7;
            int row = q * 16 + (lane >> 2);
            int gc  = (lane & 3) ^ ((row >> 1) & 3);
            gl2lds16(Bbase + (long)row * H_ + kt + hs * 32 + gc * 8,
                     (void*)(b_sh + hs * 4096 + q * 512));
        }
        // ---- stage A: f32 global->VGPR, cvt once, bf16 ds_write (padded stride) ----
        float4 av[2][4];
        #pragma unroll
        for (int hs = 0; hs < 2; ++hs) {
            const float4* src = reinterpret_cast<const float4*>(
                Abase + (long)arow * H_ + kt + hs * 32 + aseg * 16);
            av[hs][0] = src[0]; av[hs][1] = src[1];
            av[hs][2] = src[2]; av[hs][3] = src[3];
        }
        #pragma unroll
        for (int hs = 0; hs < 2; ++hs) {
            bf16* dst = a_sh + hs * (128 * ASTRIDE) + arow * ASTRIDE + aseg * 16;
            *reinterpret_cast<bf16x8*>(dst)     = cvt8(av[hs][0], av[hs][1]);
            *reinterpret_cast<bf16x8*>(dst + 8) = cvt8(av[hs][2], av[hs][3]);
        }
        __syncthreads();

        #pragma unroll
        for (int hs = 0; hs < 2; ++hs) {
            bf16x8 af[4], bg[4];
            #pragma unroll
            for (int mi = 0; mi < 4; ++mi) {
                int r = wm * 64 + mi * 16 + lrow;
                af[mi] = *reinterpret_cast<const bf16x8*>(
                    a_sh + hs * (128 * ASTRIDE) + r * ASTRIDE + quad * 8);
            }
            #pragma unroll
            for (int ni = 0; ni < 4; ++ni) {
                int r = wn * 64 + ni * 16 + lrow;
                int p = quad ^ ((r >> 1) & 3);
                bg[ni] = *reinterpret_cast<const bf16x8*>(
                    b_sh + hs * 4096 + r * 32 + p * 8);
            }
            #pragma unroll
            for (int mi = 0; mi < 4; ++mi)
                #pragma unroll
                for (int ni = 0; ni < 4; ++ni)
                    acc[mi][ni] = __builtin_amdgcn_mfma_f32_16x16x32_bf16(
                        af[mi], bg[ni], acc[mi][ni], 0, 0, 0);
        }
        __syncthreads();
    }

    // epilogue: tanh(acc + b1 + q2) * V, reduce over u, atomic into score
    const int bb = (int)(m0 / S_);
    float bq[4], vv[4];
    #pragma unroll
    for (int ni = 0; ni < 4; ++ni) {
        int u = n0 + wn * 64 + ni * 16 + lrow;
        bq[ni] = b1[u] + q2[bb * U_ + u];
        vv[ni] = V[u];
    }
    #pragma unroll
    for (int mi = 0; mi < 4; ++mi) {
        #pragma unroll
        for (int r = 0; r < 4; ++r) {
            float s = 0.f;
            #pragma unroll
            for (int ni = 0; ni < 4; ++ni) {
                float x = acc[mi][ni][r] + bq[ni];
                float t = 1.f - 2.f / (__expf(2.f * x) + 1.f);   // tanh
                s += t * vv[ni];
            }
            s += __shfl_xor(s, 1); s += __shfl_xor(s, 2);
            s += __shfl_xor(s, 4); s += __shfl_xor(s, 8);
            if (lrow == 0)
                atomicAdd(score + m0 + wm * 64 + mi * 16 + quad * 4 + r, s);
        }
    }
}

// ---------------- softmax over s, in place ----------------
__global__ void softmax_kernel(float* __restrict__ attn) {
    __shared__ float sh[S_];
    __shared__ float red[8];
    int b = blockIdx.x, tid = threadIdx.x;
    float* row = attn + (long)b * S_;
    float lmax = -1e30f;
    for (int i = tid; i < S_; i += 256) { float v = row[i]; sh[i] = v; lmax = fmaxf(lmax, v); }
    #pragma unroll
    for (int m = 32; m; m >>= 1) lmax = fmaxf(lmax, __shfl_xor(lmax, m));
    if ((tid & 63) == 0) red[tid >> 6] = lmax;
    __syncthreads();
    float gmax = fmaxf(fmaxf(red[0], red[1]), fmaxf(red[2], red[3]));
    float lsum = 0.f;
    for (int i = tid; i < S_; i += 256) { float e = __expf(sh[i] - gmax); sh[i] = e; lsum += e; }
    #pragma unroll
    for (int m = 32; m; m >>= 1) lsum += __shfl_xor(lsum, m);
    if ((tid & 63) == 0) red[4 + (tid >> 6)] = lsum;
    __syncthreads();
    float inv = 1.f / (red[4] + red[5] + red[6] + red[7]);
    for (int i = tid; i < S_; i += 256) row[i] = sh[i] * inv;
}

// ---------------- context = sum_s attn * values (fp32 direct) ----------------
__global__ void context_kernel(const float* __restrict__ vals, const float* __restrict__ attn,
                               float* __restrict__ ctx /* pre-zeroed */) {
    __shared__ float a_sh[128];
    int b = blockIdx.x >> 4;
    int sc = blockIdx.x & 15;
    int tid = threadIdx.x;
    if (tid < 128) a_sh[tid] = attn[(long)b * S_ + sc * 128 + tid];
    __syncthreads();
    const float* base = vals + ((long)b * S_ + sc * 128) * H_ + tid * 4;
    float ax = 0.f, ay = 0.f, az = 0.f, aw = 0.f;
    #pragma unroll 4
    for (int s = 0; s < 128; ++s) {
        float w = a_sh[s];
        float4 v = *reinterpret_cast<const float4*>(base + (long)s * H_);
        ax += w * v.x; ay += w * v.y; az += w * v.z; aw += w * v.w;
    }
    float* c = ctx + (long)b * H_ + tid * 4;
    atomicAdd(c + 0, ax); atomicAdd(c + 1, ay);
    atomicAdd(c + 2, az); atomicAdd(c + 3, aw);
}

extern "C" void kernel_launch(void* const* d_in, const int* in_sizes, int n_in,
                              void* d_out, int out_size, void* d_ws, size_t ws_size,
                              hipStream_t stream) {
    const float* query  = (const float*)d_in[0];
    const float* values = (const float*)d_in[1];
    const float* W1     = (const float*)d_in[2];
    const float* b1     = (const float*)d_in[3];
    const float* W2     = (const float*)d_in[4];
    const float* b2     = (const float*)d_in[5];
    const float* V      = (const float*)d_in[6];
    // d_in[7] = bv: softmax-invariant, context unaffected -> unused

    char* ws = (char*)d_ws;
    bf16*  w1t = (bf16*)ws;                                  // 2 MB
    float* q2  = (float*)(ws + (size_t)U_ * H_ * 2);         // 128 KB

    float* ctx  = (float*)d_out;            // [B,H]
    float* attn = (float*)d_out + B_ * H_;  // [B,S]

    hipMemsetAsync(d_out, 0, (size_t)(B_ * H_ + B_ * S_) * sizeof(float), stream);

    prep_kernel   <<<768,            256, 0, stream>>>(W1, w1t, query, W2, b2, q2);
    score_gemm    <<<(M_ / 128) * 8, 256, 0, stream>>>(values, w1t, b1, q2, V, attn);
    softmax_kernel<<<B_,             256, 0, stream>>>(attn);
    context_kernel<<<B_ * 16,        256, 0, stream>>>(values, attn, ctx);
}